// Round 2
// baseline (133.710 us; speedup 1.0000x reference)
//
#include <hip/hip_runtime.h>
#include <math.h>

#define B_ 2
#define M_ 384
#define N_ 384
#define NCELL 40      // 10 padded-theta rows x 4 radial cells
#define SSTR 17       // pad 16 -> 17 to spread LDS banks

// Single fused kernel: per (b,m) block
//   phase 0: build theta-padded kernel table T[cell][f][oy] in LDS (40x16x16)
//   phase 1: scatter-accumulate S[cell][f] += att*w_corner*feat[n][f] (hw ds_add_f32)
//   phase 2: out[oy] = (sum_cell sum_f T[cell][f][oy] * S[cell][f]) / psi
__global__ __launch_bounds__(256) void equiconv_kernel(
    const float* __restrict__ field,   // [B][N][2]
    const float* __restrict__ center,  // [B][M][2]
    const float* __restrict__ feat,    // [B][N][8][2] -> 16 per n
    const float* __restrict__ mask,    // [B][N][1]
    const float* __restrict__ kern,    // [8][8][4][8][2][2] = 8192 floats
    float* __restrict__ out) {         // [B][M][8][2] -> 16 per (b,m)
  __shared__ float T[NCELL * 256];     // 40 KB
  __shared__ float S[NCELL * SSTR];
  __shared__ float psi_w[4];
  __shared__ float partial[16][17];

  int t = threadIdx.x;
  int bm = blockIdx.x;
  int b = bm / M_;

  // ---- phase 0: table build (coalesced float4 loads of kern) + S init ----
  // kern element s: x=s&1, y=(s>>1)&1, th=(s>>2)&7, xr=(s>>5)&3, i=(s>>7)&7, o=(s>>10)&7
  // table dst: cell=(th+1)*4+xr (+ wrap copies), f=i*2+x, oy=o*2+y
#pragma unroll
  for (int k = 0; k < 8; ++k) {
    float4 v4 = ((const float4*)kern)[k * 256 + t];
    int base = k * 256 + t;            // == s>>2
    int th = base & 7;
    int xr = (base >> 3) & 3;
    int i  = (base >> 5) & 7;
    int o  = (base >> 8) & 7;
    float vv[4] = {v4.x, v4.y, v4.z, v4.w};
#pragma unroll
    for (int e = 0; e < 4; ++e) {
      int y = e >> 1, x = e & 1;
      int dst = (i * 2 + x) * 16 + (o * 2 + y);
      T[((th + 1) * 4 + xr) * 256 + dst] = vv[e];
      if (th == 7) T[xr * 256 + dst] = vv[e];               // wrap row 0
      if (th == 0) T[(36 + xr) * 256 + dst] = vv[e];        // wrap row 9
    }
  }
  for (int j = t; j < NCELL * SSTR; j += 256) S[j] = 0.f;
  if (t < 4) psi_w[t] = 0.f;
  __syncthreads();

  // ---- phase 1: scatter ----
  float cx = center[bm * 2 + 0];
  float cy = center[bm * 2 + 1];
  const float invR = 1.0f / 1.5f;
  const float four_over_pi = 4.0f / 3.14159265358979323846f;
  float psi_acc = 0.f;

  for (int n = t; n < N_; n += 256) {
    int fn = b * N_ + n;
    float fx = field[fn * 2 + 0];
    float fy = field[fn * 2 + 1];
    float rx = (fx - cx) * invR;
    float ry = (fy - cy) * invR;
    float r2 = rx * rx + ry * ry;
    float onem = 1.f - r2;
    float att = onem * onem * onem;
    if (att <= 0.f) continue;          // relu: zero contribution (incl. psi)
    att *= mask[fn];
    if (att == 0.f) continue;

    psi_acc += att;

    float r = sqrtf(r2 + 1e-9f);
    float theta = (rx == 0.f && ry == 0.f) ? 0.f : atan2f(ry, rx);
    float ix = 4.f * r - 0.5f;                 // radial grid coord
    float iy = theta * four_over_pi + 4.5f;    // theta grid coord (padded)
    float x0f = floorf(ix), y0f = floorf(iy);
    float wx = ix - x0f, wy = iy - y0f;
    int x0 = (int)x0f, y0 = (int)y0f;
    float wx0 = 1.f - wx, wx1 = wx;
    float wy0 = 1.f - wy, wy1 = wy;

    const float4* fp = (const float4*)(feat + fn * 16);
    float4 f0 = fp[0], f1 = fp[1], f2 = fp[2], f3 = fp[3];

#define DO_CORNER(X, Y, W)                                                   \
    do {                                                                     \
      int xc = (X), yc = (Y);                                                \
      if ((unsigned)xc <= 3u && (unsigned)yc <= 9u) {                        \
        float s = att * (W);                                                 \
        float* Sp = &S[(yc * 4 + xc) * SSTR];                                \
        unsafeAtomicAdd(Sp + 0, s * f0.x);  unsafeAtomicAdd(Sp + 1, s * f0.y);  \
        unsafeAtomicAdd(Sp + 2, s * f0.z);  unsafeAtomicAdd(Sp + 3, s * f0.w);  \
        unsafeAtomicAdd(Sp + 4, s * f1.x);  unsafeAtomicAdd(Sp + 5, s * f1.y);  \
        unsafeAtomicAdd(Sp + 6, s * f1.z);  unsafeAtomicAdd(Sp + 7, s * f1.w);  \
        unsafeAtomicAdd(Sp + 8, s * f2.x);  unsafeAtomicAdd(Sp + 9, s * f2.y);  \
        unsafeAtomicAdd(Sp + 10, s * f2.z); unsafeAtomicAdd(Sp + 11, s * f2.w); \
        unsafeAtomicAdd(Sp + 12, s * f3.x); unsafeAtomicAdd(Sp + 13, s * f3.y); \
        unsafeAtomicAdd(Sp + 14, s * f3.z); unsafeAtomicAdd(Sp + 15, s * f3.w); \
      }                                                                      \
    } while (0)

    DO_CORNER(x0,     y0,     wx0 * wy0);
    DO_CORNER(x0 + 1, y0,     wx1 * wy0);
    DO_CORNER(x0,     y0 + 1, wx0 * wy1);
    DO_CORNER(x0 + 1, y0 + 1, wx1 * wy1);
#undef DO_CORNER
  }

  // psi: butterfly reduce over the 64-lane wave, one LDS store per wave
#pragma unroll
  for (int off = 32; off > 0; off >>= 1)
    psi_acc += __shfl_xor(psi_acc, off, 64);
  if ((t & 63) == 0) psi_w[t >> 6] = psi_acc;
  __syncthreads();

  // ---- phase 2: contraction out[oy] = sum_cell sum_f T[cell][f][oy]*S[cell][f]
  int oy = t & 15, g = t >> 4;
  float acc = 0.f;
  for (int cell = g; cell < NCELL; cell += 16) {
    const float* tp = &T[cell * 256 + oy];
    const float* Sp = &S[cell * SSTR];
#pragma unroll
    for (int f = 0; f < 16; ++f) acc += tp[f * 16] * Sp[f];  // Sp[f] broadcast
  }
  partial[g][oy] = acc;
  __syncthreads();

  if (t < 16) {
    float sum = 0.f;
#pragma unroll
    for (int gg = 0; gg < 16; ++gg) sum += partial[gg][t];
    float psi = psi_w[0] + psi_w[1] + psi_w[2] + psi_w[3];
    if (psi == 0.f) psi = 1.f;
    out[bm * 16 + t] = sum / psi;
  }
}

extern "C" void kernel_launch(void* const* d_in, const int* in_sizes, int n_in,
                              void* d_out, int out_size, void* d_ws, size_t ws_size,
                              hipStream_t stream) {
  (void)in_sizes; (void)n_in; (void)out_size; (void)d_ws; (void)ws_size;
  const float* field  = (const float*)d_in[0];
  const float* center = (const float*)d_in[1];
  const float* feat   = (const float*)d_in[2];
  const float* mask   = (const float*)d_in[3];
  const float* kern   = (const float*)d_in[4];
  float* out = (float*)d_out;

  equiconv_kernel<<<dim3(B_ * M_), dim3(256), 0, stream>>>(
      field, center, feat, mask, kern, out);
}

// Round 3
// 84.260 us; speedup vs baseline: 1.5869x; 1.5869x over previous
//
#include <hip/hip_runtime.h>
#include <math.h>

#define B_ 2
#define M_ 384
#define N_ 384
#define NTY 10            // padded theta rows
#define NSLOT 640         // 40 cells x 16 f

// One block per (b,m). No atomics in the hot path.
// Phase A: compact active n into LDS (x0y0, wx/wy, g = att*feat).
// Phase B: lane = (f, xr); 10 ty-cells as register accumulators; loop the
//          compacted list with wave-uniform index (all LDS reads broadcast).
// Phase C: 4-wave reduce of S, then contraction with kern (direct indexed
//          global reads, 32KB table L1-resident), psi divide, store.
__global__ __launch_bounds__(256) void equiconv_kernel(
    const float* __restrict__ field,   // [B][N][2]
    const float* __restrict__ center,  // [B][M][2]
    const float* __restrict__ feat,    // [B][N][8][2] -> 16 per n
    const float* __restrict__ mask,    // [B][N][1]
    const float* __restrict__ kern,    // [8][8][4][8][2][2] = 8192 floats
    float* __restrict__ out) {         // [B][M][8][2] -> 16 per (b,m)
  __shared__ int    sX0Y0[N_];
  __shared__ float2 sW[N_];
  __shared__ float4 sG4[N_ * 4];       // g[a][f], 16 floats per active n
  __shared__ float  sS4[4][NSLOT];     // per-wave partial S
  __shared__ float  sS[NSLOT];
  __shared__ float  sPartial[16][17];
  __shared__ float  sPsi[4];
  __shared__ int    sCnt;

  int t = threadIdx.x;
  int bm = blockIdx.x;
  int b = bm / M_;

  if (t == 0) sCnt = 0;
  if (t < 4) sPsi[t] = 0.f;
  __syncthreads();

  // ---- Phase A: geometry + compaction ----
  float cx = center[bm * 2 + 0];
  float cy = center[bm * 2 + 1];
  const float invR = 1.0f / 1.5f;
  const float fourpi = 4.0f / 3.14159265358979323846f;
  float psi_acc = 0.f;

  for (int n = t; n < N_; n += 256) {
    int fn = b * N_ + n;
    float rx = (field[fn * 2 + 0] - cx) * invR;
    float ry = (field[fn * 2 + 1] - cy) * invR;
    float r2 = rx * rx + ry * ry;
    float onem = 1.f - r2;
    float att = onem * onem * onem;
    if (att <= 0.f) continue;          // relu: zero contribution incl. psi
    att *= mask[fn];
    if (att == 0.f) continue;

    psi_acc += att;

    float r = sqrtf(r2 + 1e-9f);
    float theta = (rx == 0.f && ry == 0.f) ? 0.f : atan2f(ry, rx);
    float ix = 4.f * r - 0.5f;                 // radial coord, x0 in {-1..3}
    float iy = theta * fourpi + 4.5f;          // theta coord in (0.5, 8.5]
    float x0f = floorf(ix), y0f = floorf(iy);
    int x0 = (int)x0f, y0 = (int)y0f;          // y0 in {0..8} always

    int a = atomicAdd(&sCnt, 1);               // compiler wave-aggregates
    sX0Y0[a] = (x0 + 1) | (y0 << 8);
    sW[a] = make_float2(ix - x0f, iy - y0f);
    const float4* fp = (const float4*)(feat + fn * 16);
    float4* gp = &sG4[a * 4];
#pragma unroll
    for (int q = 0; q < 4; ++q) {
      float4 v = fp[q];
      v.x *= att; v.y *= att; v.z *= att; v.w *= att;
      gp[q] = v;
    }
  }

  // psi: butterfly reduce per wave
#pragma unroll
  for (int off = 32; off > 0; off >>= 1)
    psi_acc += __shfl_xor(psi_acc, off, 64);
  if ((t & 63) == 0) sPsi[t >> 6] = psi_acc;
  __syncthreads();
  int cnt = sCnt;

  // ---- Phase B: owner-computes gather, register accumulators ----
  int f  = t & 15;
  int xr = (t >> 4) & 3;
  int w  = t >> 6;
  const float* sG = (const float*)sG4;

  float acc[NTY];
#pragma unroll
  for (int k = 0; k < NTY; ++k) acc[k] = 0.f;

  int chunk = (cnt + 3) >> 2;
  int a0 = w * chunk;
  int a1 = min(a0 + chunk, cnt);
  for (int a = a0; a < a1; ++a) {
    int meta = sX0Y0[a];                 // broadcast read
    float2 wv = sW[a];                   // broadcast read
    float g = sG[a * 16 + f];            // 16-addr, conflict-free
    int x0 = (meta & 255) - 1;
    int y0 = meta >> 8;
    float wx1 = wv.x, wy1 = wv.y;
    float ux = (xr == x0) ? (1.f - wx1) : ((xr == x0 + 1) ? wx1 : 0.f);
    float ug = ux * g;
    float wy0 = 1.f - wy1;
#pragma unroll
    for (int k = 0; k < NTY; ++k) {
      float vy = (k == y0) ? wy0 : ((k == y0 + 1) ? wy1 : 0.f);
      acc[k] = fmaf(ug, vy, acc[k]);
    }
  }
#pragma unroll
  for (int k = 0; k < NTY; ++k)
    sS4[w][(k * 4 + xr) * 16 + f] = acc[k];
  __syncthreads();

  // ---- Phase C: cross-wave reduce, contraction, output ----
  for (int s = t; s < NSLOT; s += 256)
    sS[s] = sS4[0][s] + sS4[1][s] + sS4[2][s] + sS4[3][s];
  __syncthreads();

  // out[oy] = sum_{cell,f} kern[o][i][xr][th(ty)][y][x] * S[cell][f]
  int oy = t & 15, grp = t >> 4;
  int o = oy >> 1, y = oy & 1;
  float cacc = 0.f;
  for (int c = grp; c < 40; c += 16) {
    int ty = c >> 2, cxr = c & 3;
    int th = (ty + 7) & 7;               // circular theta pad
    const float* sp = &sS[c * 16];
#pragma unroll
    for (int ff = 0; ff < 16; ++ff) {
      int i = ff >> 1, x = ff & 1;
      int idx = ((((o * 8 + i) * 4 + cxr) * 8 + th) * 2 + y) * 2 + x;
      cacc = fmaf(kern[idx], sp[ff], cacc);
    }
  }
  sPartial[grp][oy] = cacc;
  __syncthreads();

  if (t < 16) {
    float sum = 0.f;
#pragma unroll
    for (int gg = 0; gg < 16; ++gg) sum += sPartial[gg][t];
    float psi = sPsi[0] + sPsi[1] + sPsi[2] + sPsi[3];
    if (psi == 0.f) psi = 1.f;
    out[bm * 16 + t] = sum / psi;
  }
}

extern "C" void kernel_launch(void* const* d_in, const int* in_sizes, int n_in,
                              void* d_out, int out_size, void* d_ws, size_t ws_size,
                              hipStream_t stream) {
  (void)in_sizes; (void)n_in; (void)out_size; (void)d_ws; (void)ws_size;
  const float* field  = (const float*)d_in[0];
  const float* center = (const float*)d_in[1];
  const float* feat   = (const float*)d_in[2];
  const float* mask   = (const float*)d_in[3];
  const float* kern   = (const float*)d_in[4];
  float* out = (float*)d_out;

  equiconv_kernel<<<dim3(B_ * M_), dim3(256), 0, stream>>>(
      field, center, feat, mask, kern, out);
}

// Round 4
// 83.111 us; speedup vs baseline: 1.6088x; 1.0138x over previous
//
#include <hip/hip_runtime.h>
#include <math.h>

#define B_ 2
#define M_ 384
#define N_ 384
#define NTY 10            // padded theta rows
#define NSLOT 640         // 40 cells x 16 f
#define NW 8              // waves per block
#define BS 512            // block size

// Pre-permuted, theta-wrapped kernel table: table[cell][f][oy]
// cell = tw*4+xr (tw: 10 padded theta rows), f = i*2+x, oy = o*2+y
__global__ __launch_bounds__(256) void build_table_kernel(
    const float* __restrict__ kern, float* __restrict__ table) {
  int cell = blockIdx.x;          // 0..39
  int t = threadIdx.x;            // 0..255 == f*16 + oy
  int f = t >> 4, oy = t & 15;
  int tw = cell >> 2, xr = cell & 3;
  int th = (tw == 0) ? 7 : ((tw == 9) ? 0 : (tw - 1));  // circular theta pad
  int o = oy >> 1, y = oy & 1, i = f >> 1, x = f & 1;
  int src = ((((o * 8 + i) * 4 + xr) * 8 + th) * 2 + y) * 2 + x;
  table[cell * 256 + t] = kern[src];
}

struct F2 { float x, y; };

// Overlay: phase-A staging (meta,w) is dead once phase B finishes; reuse the
// space for the phase-C reduced S and partial buffers.
union SmemU {
  struct { int meta[N_]; F2 w[N_]; } a;                   // 4608 B
  struct { float S[NSLOT]; float partial[16][17]; } c;    // 3648 B
};

__global__ __launch_bounds__(BS) void equiconv_kernel(
    const float* __restrict__ field,   // [B][N][2]
    const float* __restrict__ center,  // [B][M][2]
    const float* __restrict__ feat,    // [B][N][8][2] -> 16 per n
    const float* __restrict__ mask,    // [B][N][1]
    const float* __restrict__ table,   // [40][16][16] in d_ws
    float* __restrict__ out) {         // [B][M][8][2] -> 16 per (b,m)
  __shared__ SmemU u;
  __shared__ float4 sG4[N_ * 4];      // 24576 B: att*feat per active n
  __shared__ float sS4[NW][NSLOT];    // 20480 B: per-wave partial S
  __shared__ float sPsi[NW];
  __shared__ int sCnt;

  int t = threadIdx.x;
  int bm = blockIdx.x;
  int b = bm / M_;

  if (t == 0) sCnt = 0;
  if (t < NW) sPsi[t] = 0.f;
  __syncthreads();

  // ---- Phase A: geometry + compaction into LDS ----
  float cx = center[bm * 2 + 0];
  float cy = center[bm * 2 + 1];
  const float invR = 1.0f / 1.5f;
  const float fourpi = 4.0f / 3.14159265358979323846f;
  float psi_acc = 0.f;

  for (int n = t; n < N_; n += BS) {
    int fn = b * N_ + n;
    float rx = (field[fn * 2 + 0] - cx) * invR;
    float ry = (field[fn * 2 + 1] - cy) * invR;
    float r2 = rx * rx + ry * ry;
    float onem = 1.f - r2;
    float att = onem * onem * onem;
    if (att <= 0.f) continue;          // relu: zero contribution incl. psi
    att *= mask[fn];
    if (att == 0.f) continue;

    psi_acc += att;

    float r = sqrtf(r2 + 1e-9f);
    float theta = (rx == 0.f && ry == 0.f) ? 0.f : atan2f(ry, rx);
    float ix = 4.f * r - 0.5f;                 // radial coord, x0 in {-1..3}
    float iy = theta * fourpi + 4.5f;          // theta coord in (0.5, 8.5]
    float x0f = floorf(ix), y0f = floorf(iy);
    int x0 = (int)x0f, y0 = (int)y0f;          // y0 in {0..8}

    int a = atomicAdd(&sCnt, 1);               // ds_add_rtn, wave-aggregated
    u.a.meta[a] = (x0 + 1) | (y0 << 8);
    u.a.w[a].x = ix - x0f;
    u.a.w[a].y = iy - y0f;
    const float4* fp = (const float4*)(feat + fn * 16);
    float4* gp = &sG4[a * 4];
#pragma unroll
    for (int q = 0; q < 4; ++q) {
      float4 v = fp[q];
      v.x *= att; v.y *= att; v.z *= att; v.w *= att;
      gp[q] = v;
    }
  }

  // psi: butterfly reduce per wave, one store per wave
#pragma unroll
  for (int off = 32; off > 0; off >>= 1)
    psi_acc += __shfl_xor(psi_acc, off, 64);
  if ((t & 63) == 0) sPsi[t >> 6] = psi_acc;
  __syncthreads();
  int cnt = sCnt;

  // ---- Phase B: owner-computes gather, scalarized uniform control data ----
  int f   = t & 15;
  int xr4 = (t >> 4) & 3;
  int w   = t >> 6;
  const float* sG = (const float*)sG4;

  float acc[NTY];
#pragma unroll
  for (int k = 0; k < NTY; ++k) acc[k] = 0.f;

  int chunk = (cnt + NW - 1) / NW;
  int a0 = w * chunk;
  int a1 = min(a0 + chunk, cnt);
#pragma unroll 2
  for (int a = a0; a < a1; ++a) {
    // all lanes read the same address -> value is wave-uniform; force SGPRs
    int meta = __builtin_amdgcn_readfirstlane(u.a.meta[a]);
    F2 wv = u.a.w[a];
    float wx1 = __int_as_float(__builtin_amdgcn_readfirstlane(__float_as_int(wv.x)));
    float wy1 = __int_as_float(__builtin_amdgcn_readfirstlane(__float_as_int(wv.y)));
    float g = sG[a * 16 + f];            // 16-addr read, conflict-free
    int x0 = (meta & 255) - 1;           // scalar
    int y0 = meta >> 8;                  // scalar
    float ux = (xr4 == x0) ? (1.f - wx1) : ((xr4 == x0 + 1) ? wx1 : 0.f);
    float ug = ux * g;
    float wy0 = 1.f - wy1;
#pragma unroll
    for (int k = 0; k < NTY; ++k) {
      // y0, wy0, wy1 scalar -> vy resolves to s_cselect chain (SALU),
      // each fma is one VALU with a single SGPR operand
      float vy = (k == y0) ? wy0 : ((k == y0 + 1) ? wy1 : 0.f);
      acc[k] = fmaf(vy, ug, acc[k]);
    }
  }
#pragma unroll
  for (int k = 0; k < NTY; ++k)
    sS4[w][(k * 4 + xr4) * 16 + f] = acc[k];
  __syncthreads();   // phase-A staging dead from here; u.c overlays it

  // ---- Phase C: cross-wave reduce, contraction with table, output ----
  for (int s = t; s < NSLOT; s += BS) {
    float v = 0.f;
#pragma unroll
    for (int ww = 0; ww < NW; ++ww) v += sS4[ww][s];
    u.c.S[s] = v;
  }
  __syncthreads();

  if (t < 256) {
    int oy = t & 15, grp = t >> 4;
    float cacc = 0.f;
    for (int c = grp; c < 40; c += 16) {
      const float* tp = table + c * 256 + oy;   // contiguous over oy: coalesced
      const float* sp = &u.c.S[c * 16];
#pragma unroll
      for (int ff = 0; ff < 16; ++ff)
        cacc = fmaf(tp[ff * 16], sp[ff], cacc);
    }
    u.c.partial[grp][oy] = cacc;
  }
  __syncthreads();

  if (t < 16) {
    float sum = 0.f;
#pragma unroll
    for (int gg = 0; gg < 16; ++gg) sum += u.c.partial[gg][t];
    float psi = 0.f;
#pragma unroll
    for (int ww = 0; ww < NW; ++ww) psi += sPsi[ww];
    if (psi == 0.f) psi = 1.f;
    out[bm * 16 + t] = sum / psi;
  }
}

extern "C" void kernel_launch(void* const* d_in, const int* in_sizes, int n_in,
                              void* d_out, int out_size, void* d_ws, size_t ws_size,
                              hipStream_t stream) {
  (void)in_sizes; (void)n_in; (void)out_size; (void)ws_size;
  const float* field  = (const float*)d_in[0];
  const float* center = (const float*)d_in[1];
  const float* feat   = (const float*)d_in[2];
  const float* mask   = (const float*)d_in[3];
  const float* kern   = (const float*)d_in[4];
  float* out = (float*)d_out;
  float* table = (float*)d_ws;  // 40*256 floats = 40960 B, rebuilt every launch

  build_table_kernel<<<dim3(40), dim3(256), 0, stream>>>(kern, table);
  equiconv_kernel<<<dim3(B_ * M_), dim3(BS), 0, stream>>>(
      field, center, feat, mask, table, out);
}

// Round 5
// 82.890 us; speedup vs baseline: 1.6131x; 1.0027x over previous
//
#include <hip/hip_runtime.h>
#include <math.h>

#define B_ 2
#define M_ 384
#define N_ 384
#define NTY 10            // padded theta rows
#define NSLOT 640         // 40 cells x 16 f
#define NW 4              // waves per block
#define BS 256

// Inline minimax atan2 (max err ~1e-5 rad; reference threshold is 0.115 on
// outputs, current absmax 0.002 -> safe). Avoids the branchy ocml libcall.
__device__ __forceinline__ float fast_atan2f(float y, float x) {
  float ax = fabsf(x), ay = fabsf(y);
  float mx = fmaxf(ax, ay), mn = fminf(ax, ay);
  float a = mn * __builtin_amdgcn_rcpf(mx);
  if (mx == 0.f) a = 0.f;              // rx==ry==0 -> theta 0 (matches ref)
  float s = a * a;
  float p = -0.0117212f;
  p = fmaf(p, s, 0.05265332f);
  p = fmaf(p, s, -0.11643287f);
  p = fmaf(p, s, 0.19354346f);
  p = fmaf(p, s, -0.33262347f);
  p = fmaf(p, s, 0.99997726f);
  float r = p * a;                     // atan(mn/mx) in [0, pi/4]
  if (ay > ax) r = 1.57079632679f - r;
  if (x < 0.f) r = 3.14159265359f - r;
  return (y < 0.f) ? -r : r;
}

// One block per (b,m), 4 waves, single dispatch, no atomics in hot path.
__global__ __launch_bounds__(BS) void equiconv_kernel(
    const float* __restrict__ field,   // [B][N][2]
    const float* __restrict__ center,  // [B][M][2]
    const float* __restrict__ feat,    // [B][N][8][2] -> 16 per n
    const float* __restrict__ mask,    // [B][N][1]
    const float* __restrict__ kern,    // [8][8][4][8][2][2] = 8192 floats
    float* __restrict__ out) {         // [B][M][8][2] -> 16 per (b,m)
  __shared__ float4 sMeta[N_];         // {bits(x0y0), wx, wy, -} per active n
  __shared__ float4 sG4[N_ * 4];       // att*feat, 16 floats per active n
  __shared__ float  sS4[NW][NSLOT];    // per-wave partial S
  __shared__ float  sS[NSLOT];
  __shared__ float  sPartial[16][17];
  __shared__ float  sPsi[NW];
  __shared__ int    sCnt;

  int t = threadIdx.x;
  int bm = blockIdx.x;
  int b = bm / M_;

  if (t == 0) sCnt = 0;
  if (t < NW) sPsi[t] = 0.f;
  __syncthreads();

  // ---- Phase A: straight-line geometry, speculative loads, one branch ----
  float cx = center[bm * 2 + 0];
  float cy = center[bm * 2 + 1];
  const float invR = 1.0f / 1.5f;
  const float fourpi = 4.0f / 3.14159265358979323846f;
  float psi_acc = 0.f;

  for (int n = t; n < N_; n += BS) {
    int fn = b * N_ + n;
    float2 fxy = ((const float2*)field)[fn];
    float msk = mask[fn];
    const float4* fp = (const float4*)(feat + fn * 16);
    float4 f0 = fp[0], f1 = fp[1], f2 = fp[2], f3 = fp[3];  // speculative

    float rx = (fxy.x - cx) * invR;
    float ry = (fxy.y - cy) * invR;
    float r2 = rx * rx + ry * ry;
    float onem = 1.f - r2;
    float attr = onem * onem * onem;
    float att = attr * msk;

    // speculative geometry (straight-line, no libcall)
    float r = sqrtf(r2 + 1e-9f);
    float theta = fast_atan2f(ry, rx);
    float ix = 4.f * r - 0.5f;                 // x0 in {-1..3}
    float iy = theta * fourpi + 4.5f;          // in (0.5, 8.5]
    float x0f = floorf(ix), y0f = floorf(iy);
    int x0 = (int)x0f, y0 = (int)y0f;

    if (attr > 0.f && att != 0.f) {            // relu gate, then mask gate
      psi_acc += att;
      int a = atomicAdd(&sCnt, 1);             // wave-aggregated ds_add_rtn
      sMeta[a] = make_float4(
          __int_as_float((x0 + 1) | (y0 << 8)), ix - x0f, iy - y0f, 0.f);
      float4* gp = &sG4[a * 4];
      f0.x *= att; f0.y *= att; f0.z *= att; f0.w *= att;
      f1.x *= att; f1.y *= att; f1.z *= att; f1.w *= att;
      f2.x *= att; f2.y *= att; f2.z *= att; f2.w *= att;
      f3.x *= att; f3.y *= att; f3.z *= att; f3.w *= att;
      gp[0] = f0; gp[1] = f1; gp[2] = f2; gp[3] = f3;
    }
  }

  // psi: butterfly reduce per wave
#pragma unroll
  for (int off = 32; off > 0; off >>= 1)
    psi_acc += __shfl_xor(psi_acc, off, 64);
  if ((t & 63) == 0) sPsi[t >> 6] = psi_acc;
  __syncthreads();
  int cnt = sCnt;

  // ---- Phase B: owner-computes gather (lane = f,xr), reg accumulators ----
  int f   = t & 15;
  int xr4 = (t >> 4) & 3;
  int w   = t >> 6;
  const float* sG = (const float*)sG4;

  float acc[NTY];
#pragma unroll
  for (int k = 0; k < NTY; ++k) acc[k] = 0.f;

  int chunk = (cnt + NW - 1) / NW;
  int a0 = w * chunk;
  int a1 = min(a0 + chunk, cnt);
#pragma unroll 2
  for (int a = a0; a < a1; ++a) {
    float4 md = sMeta[a];                // one b128 broadcast read
    float g = sG[a * 16 + f];            // 16-addr, 4-lane broadcast each: free
    int meta = __float_as_int(md.x);
    int x0 = (meta & 255) - 1;
    int y0 = meta >> 8;
    float wx1 = md.y, wy1 = md.z;
    float ux = (xr4 == x0) ? (1.f - wx1) : ((xr4 == x0 + 1) ? wx1 : 0.f);
    float ug = ux * g;
    float wy0 = 1.f - wy1;
#pragma unroll
    for (int k = 0; k < NTY; ++k) {
      float vy = (k == y0) ? wy0 : ((k == y0 + 1) ? wy1 : 0.f);
      acc[k] = fmaf(vy, ug, acc[k]);
    }
  }
#pragma unroll
  for (int k = 0; k < NTY; ++k)
    sS4[w][(k * 4 + xr4) * 16 + f] = acc[k];
  __syncthreads();

  // ---- Phase C: cross-wave reduce + contraction + output ----
  for (int s = t; s < NSLOT; s += BS) {
    float v = sS4[0][s] + sS4[1][s] + sS4[2][s] + sS4[3][s];
    sS[s] = v;
  }
  __syncthreads();

  {
    int oy = t & 15, grp = t >> 4;
    int o = oy >> 1, y = oy & 1;
    float cacc = 0.f;
    for (int c = grp; c < 40; c += 16) {
      int ty = c >> 2, cxr = c & 3;
      int th = (ty + 7) & 7;             // circular theta pad
      const float* sp = &sS[c * 16];
#pragma unroll
      for (int ff = 0; ff < 16; ++ff) {
        int i = ff >> 1, x = ff & 1;
        int idx = ((((o * 8 + i) * 4 + cxr) * 8 + th) * 2 + y) * 2 + x;
        cacc = fmaf(kern[idx], sp[ff], cacc);
      }
    }
    sPartial[grp][oy] = cacc;
  }
  __syncthreads();

  if (t < 16) {
    float sum = 0.f;
#pragma unroll
    for (int gg = 0; gg < 16; ++gg) sum += sPartial[gg][t];
    float psi = sPsi[0] + sPsi[1] + sPsi[2] + sPsi[3];
    if (psi == 0.f) psi = 1.f;
    out[bm * 16 + t] = sum / psi;
  }
}

extern "C" void kernel_launch(void* const* d_in, const int* in_sizes, int n_in,
                              void* d_out, int out_size, void* d_ws, size_t ws_size,
                              hipStream_t stream) {
  (void)in_sizes; (void)n_in; (void)out_size; (void)d_ws; (void)ws_size;
  const float* field  = (const float*)d_in[0];
  const float* center = (const float*)d_in[1];
  const float* feat   = (const float*)d_in[2];
  const float* mask   = (const float*)d_in[3];
  const float* kern   = (const float*)d_in[4];
  float* out = (float*)d_out;

  equiconv_kernel<<<dim3(B_ * M_), dim3(BS), 0, stream>>>(
      field, center, feat, mask, kern, out);
}